// Round 4
// baseline (4563.461 us; speedup 1.0000x reference)
//
#include <hip/hip_runtime.h>
#include <hip/hip_bf16.h>

// GNODE fully fused: y' = relu(y@W1+b1)@W2+b2, RK4(3/8) x10 steps (h=0.1),
// out = y@Wl+bl.  N=200000 rows, 128 ch, 64 out ch.
//
// Round 4: weights moved from VGPRs to LDS (round 3 spilled ~460MB: weights
// alone were 256 regs).  W1/W2 A-frags staged in 64KB LDS, ds_read_b128 per
// MFMA (lane-contiguous -> conflict-free; LDS pipe ~3% loaded vs matrix
// window).  Live regs: y/ka/kb/s 128 + biases 32 + frags/acc/h ~64 => ~256.
// __launch_bounds__(256,2): 256-VGPR cap, 2 waves/SIMD (2 blocks/CU @ 64KB).
// Wl loaded from global in epilogue (after ka/kb/s die).
//
// Layout identity (mfma_f32_16x16x32_bf16, HW-verified m89):
//   D:      ch = 16*mb + 4*(lane>>4) + r,               batch = lane&15
//   B-frag: ch = 32*kb + 16*(j>>2) + 4*(lane>>4)+(j&3),  batch = lane&15
// => frag[e>>3][e&7] = state[e], e = 4*mb + r.  All lane-local.

typedef __attribute__((ext_vector_type(8))) short bf16x8;
typedef __attribute__((ext_vector_type(4))) float f32x4;

constexpr float HS = 0.1f;

__device__ __forceinline__ short bf16s(float f) {
    return (short)__builtin_bit_cast(unsigned short, __float2bfloat16(f));
}
__device__ __forceinline__ float bplo(unsigned u) { return __builtin_bit_cast(float, u << 16); }
__device__ __forceinline__ float bphi(unsigned u) { return __builtin_bit_cast(float, u & 0xffff0000u); }

__device__ __forceinline__ void bias_init(const unsigned (&bp)[16], f32x4 (&acc)[8]) {
    #pragma unroll
    for (int mb = 0; mb < 8; ++mb) {
        acc[mb][0] = bplo(bp[mb * 2 + 0]);
        acc[mb][1] = bphi(bp[mb * 2 + 0]);
        acc[mb][2] = bplo(bp[mb * 2 + 1]);
        acc[mb][3] = bphi(bp[mb * 2 + 1]);
    }
}

// acc += W @ in, W frags from LDS (32 x ds_read_b128, lane-contiguous).
__device__ __forceinline__ void mm_core(const uint4* __restrict__ sw, int lane,
                                        const bf16x8 (&in)[4], f32x4 (&acc)[8]) {
    #pragma unroll
    for (int kb = 0; kb < 4; ++kb)          // inner mb: 8 independent accs
        #pragma unroll
        for (int mb = 0; mb < 8; ++mb) {
            bf16x8 w = __builtin_bit_cast(bf16x8, sw[(mb * 4 + kb) * 64 + lane]);
            acc[mb] = __builtin_amdgcn_mfma_f32_16x16x32_bf16(w, in[kb], acc[mb], 0, 0, 0);
        }
}

// kout = W2 @ relu(W1 @ in + b1) + b2 ; h kept only as bf16 frags.
__device__ __forceinline__ void feval(const uint4* __restrict__ sw1, const uint4* __restrict__ sw2,
                                      int lane,
                                      const unsigned (&b1p)[16], const unsigned (&b2p)[16],
                                      const bf16x8 (&in)[4], float (&kout)[32])
{
    f32x4 acc[8];
    bias_init(b1p, acc);
    mm_core(sw1, lane, in, acc);
    bf16x8 h[4];
    #pragma unroll
    for (int mb = 0; mb < 8; ++mb)
        #pragma unroll
        for (int r = 0; r < 4; ++r)
            h[mb >> 1][(mb & 1) * 4 + r] = bf16s(fmaxf(acc[mb][r], 0.f));
    f32x4 acc2[8];
    bias_init(b2p, acc2);
    mm_core(sw2, lane, h, acc2);
    #pragma unroll
    for (int mb = 0; mb < 8; ++mb)
        #pragma unroll
        for (int r = 0; r < 4; ++r)
            kout[mb * 4 + r] = acc2[mb][r];
}

__global__ __launch_bounds__(256, 2) void gnode_kernel(
    const float* __restrict__ x, const uint4* __restrict__ wfr,
    const unsigned* __restrict__ b1pg, const unsigned* __restrict__ b2pg,
    const float* __restrict__ bl, float* __restrict__ out, int n)
{
    __shared__ uint4 s_w[4096];              // 64KB: W1 frags [0..2047], W2 [2048..4095]

    const int tid  = threadIdx.x;
    const int lane = tid & 63;
    const int wid  = tid >> 6;
    const int g    = lane >> 4;
    const int c16  = lane & 15;
    const int row  = blockIdx.x * 64 + wid * 16 + c16;   // this lane's batch row
    const int rowc = row < n ? row : n - 1;

    // ---- stage W1+W2 frags into LDS (one-time, 64KB, L2/L3-hot)
    #pragma unroll
    for (int i = 0; i < 16; ++i) s_w[i * 256 + tid] = wfr[i * 256 + tid];

    unsigned b1p[16], b2p[16];
    #pragma unroll
    for (int p = 0; p < 16; ++p) b1p[p] = b1pg[lane * 16 + p];
    #pragma unroll
    for (int p = 0; p < 16; ++p) b2p[p] = b2pg[lane * 16 + p];

    // Y^T state, fp32 master: elem e=4*mb+r <-> (ch = 16*mb+4*g+r, batch=row)
    float y[32];
    {
        const f32x4* x4 = (const f32x4*)x;
        #pragma unroll
        for (int cb = 0; cb < 8; ++cb) {
            f32x4 v = x4[(size_t)rowc * 32 + cb * 4 + g];
            y[cb * 4 + 0] = v[0]; y[cb * 4 + 1] = v[1];
            y[cb * 4 + 2] = v[2]; y[cb * 4 + 3] = v[3];
        }
    }
    __syncthreads();

    const uint4* sw1 = s_w;
    const uint4* sw2 = s_w + 2048;

    float ka[32], kb[32], s[32];
    bf16x8 fr[4];

    for (int st = 0; st < 10; ++st) {
        // k1 = f(y)
        #pragma unroll
        for (int e = 0; e < 32; ++e) fr[e >> 3][e & 7] = bf16s(y[e]);
        feval(sw1, sw2, lane, b1p, b2p, fr, ka);
        // k2 = f(y + (h/3) k1)
        #pragma unroll
        for (int e = 0; e < 32; ++e)
            fr[e >> 3][e & 7] = bf16s(fmaf(HS * (1.f / 3.f), ka[e], y[e]));
        feval(sw1, sw2, lane, b1p, b2p, fr, kb);
        // k3 = f(y + h k2 - (h/3) k1)
        #pragma unroll
        for (int e = 0; e < 32; ++e)
            fr[e >> 3][e & 7] = bf16s(fmaf(HS, kb[e], fmaf(-HS * (1.f / 3.f), ka[e], y[e])));
        feval(sw1, sw2, lane, b1p, b2p, fr, s);
        // fold: ka <- k1+3k2+3k3 ; kb <- k1-k2+k3
        #pragma unroll
        for (int e = 0; e < 32; ++e) {
            float u = kb[e];
            kb[e] = ka[e] - u + s[e];
            ka[e] = fmaf(3.f, u + s[e], ka[e]);
        }
        // k4 = f(y + h (k1-k2+k3))
        #pragma unroll
        for (int e = 0; e < 32; ++e) fr[e >> 3][e & 7] = bf16s(fmaf(HS, kb[e], y[e]));
        feval(sw1, sw2, lane, b1p, b2p, fr, s);
        // y += h/8 (ka + k4)
        #pragma unroll
        for (int e = 0; e < 32; ++e) y[e] = fmaf(HS * 0.125f, ka[e] + s[e], y[e]);
    }

    // ---- epilogue: out^T = Wl^T y^T + bl  (Wl frags straight from global)
    bf16x8 yf[4];
    #pragma unroll
    for (int e = 0; e < 32; ++e) yf[e >> 3][e & 7] = bf16s(y[e]);
    f32x4 ao[4];
    {
        const f32x4* bl4 = (const f32x4*)bl;
        #pragma unroll
        for (int mb = 0; mb < 4; ++mb) ao[mb] = bl4[mb * 4 + g];   // bl[16mb+4g+r]
    }
    #pragma unroll
    for (int f = 0; f < 16; ++f) {
        bf16x8 w = __builtin_bit_cast(bf16x8, wfr[(64 + f) * 64 + lane]);
        ao[f >> 2] = __builtin_amdgcn_mfma_f32_16x16x32_bf16(w, yf[f & 3], ao[f >> 2], 0, 0, 0);
    }
    if (row < n) {
        f32x4* out4 = (f32x4*)out;
        #pragma unroll
        for (int mb = 0; mb < 4; ++mb)
            out4[(size_t)row * 16 + mb * 4 + g] = ao[mb];          // out[row][16mb+4g+r]
    }
}

// ---- prep: A-frag-linear bf16 weights + packed-bf16 biases into d_ws ----
// A-frag (16x32): lane l, elem j:  row = l&15 (+16*mb),
//                                  k   = 32*kb + 16*(j>>2) + 4*(l>>4) + (j&3)
// wfr[f*64+lane] : f 0..31 = W1 (mb=f>>2,kb=f&3), 32..63 = W2, 64..79 = Wl.
__global__ void prep_kernel(const float* __restrict__ W1, const float* __restrict__ W2,
                            const float* __restrict__ Wl,
                            const float* __restrict__ b1, const float* __restrict__ b2,
                            uint4* __restrict__ wfr, unsigned* __restrict__ b1p,
                            unsigned* __restrict__ b2p)
{
    int t = blockIdx.x * 256 + threadIdx.x;
    if (t < 80 * 64) {
        int f = t >> 6, lane = t & 63;
        int gq = lane >> 4, c = lane & 15;
        const float* W; int mb, kv, cols;
        if (f < 32)      { W = W1; mb = f >> 2;        kv = f & 3;        cols = 128; }
        else if (f < 64) { W = W2; mb = (f - 32) >> 2; kv = (f - 32) & 3; cols = 128; }
        else             { W = Wl; mb = (f - 64) >> 2; kv = (f - 64) & 3; cols = 64;  }
        int col = mb * 16 + c;               // output-channel (A row)
        unsigned short v[8];
        #pragma unroll
        for (int j = 0; j < 8; ++j) {
            int k = kv * 32 + (j >> 2) * 16 + gq * 4 + (j & 3);
            v[j] = __builtin_bit_cast(unsigned short, __float2bfloat16(W[k * cols + col]));
        }
        uint4 o;
        o.x = (unsigned)v[0] | ((unsigned)v[1] << 16);
        o.y = (unsigned)v[2] | ((unsigned)v[3] << 16);
        o.z = (unsigned)v[4] | ((unsigned)v[5] << 16);
        o.w = (unsigned)v[6] | ((unsigned)v[7] << 16);
        wfr[t] = o;
    } else if (t < 80 * 64 + 128) {
        int u = t - 80 * 64;
        const float* b = (u < 64) ? b1 : b2;
        unsigned* dst  = (u < 64) ? b1p : b2p;
        int lane = u & 63, gq = lane >> 4;
        for (int p = 0; p < 16; ++p) {       // pair p covers state elems 2p,2p+1
            int e0 = 2 * p, e1 = 2 * p + 1;
            int ch0 = 16 * (e0 >> 2) + 4 * gq + (e0 & 3);
            int ch1 = 16 * (e1 >> 2) + 4 * gq + (e1 & 3);
            unsigned short v0 = __builtin_bit_cast(unsigned short, __float2bfloat16(b[ch0]));
            unsigned short v1 = __builtin_bit_cast(unsigned short, __float2bfloat16(b[ch1]));
            dst[lane * 16 + p] = (unsigned)v0 | ((unsigned)v1 << 16);
        }
    }
}

extern "C" void kernel_launch(void* const* d_in, const int* in_sizes, int n_in,
                              void* d_out, int out_size, void* d_ws, size_t ws_size,
                              hipStream_t stream)
{
    const float* x  = (const float*)d_in[0];
    const float* W1 = (const float*)d_in[1];
    const float* b1 = (const float*)d_in[2];
    const float* W2 = (const float*)d_in[3];
    const float* b2 = (const float*)d_in[4];
    const float* Wl = (const float*)d_in[5];
    const float* bl = (const float*)d_in[6];

    const int n = in_sizes[0] / 128;

    uint4*    wfr = (uint4*)d_ws;                                  // 80*64*16 = 81920 B
    unsigned* b1p = (unsigned*)((char*)d_ws + 81920);              // 4096 B
    unsigned* b2p = (unsigned*)((char*)d_ws + 86016);              // 4096 B

    prep_kernel<<<21, 256, 0, stream>>>(W1, W2, Wl, b1, b2, wfr, b1p, b2p);

    const int nb = (n + 63) / 64;            // 64 rows per block (4 waves x 16)
    gnode_kernel<<<nb, 256, 0, stream>>>(x, wfr, b1p, b2p, bl, (float*)d_out, n);
}

// Round 5
// 848.415 us; speedup vs baseline: 5.3788x; 5.3788x over previous
//
#include <hip/hip_runtime.h>
#include <hip/hip_bf16.h>

// GNODE fully fused: y' = relu(y@W1+b1)@W2+b2, RK4(3/8) x10 steps (h=0.1),
// out = y@Wl+bl.  N=200000 rows, 128 ch, 64 out ch.
//
// Round 5: register-diet version of round 4 (which spilled 16.8GB because
// __launch_bounds__(256,2) forced a 128-reg arch cap).  Changes:
// - no min-waves clause; allocator free to pick (~190-reg live set).
// - state arrays ka/kb/s replaced by U/V; RK4 combines folded into the
//   2nd-matmul writeback (template<MODE>):
//     M1: U<-k1          M2: V<-k2
//     M3: U<-U+3(V+k3), V<-U-V+k3      M4: y += h/8 (U + k4)
// - B-frags built just-in-time per kb (4 regs, not 16), coefficients per
//   mode: arg = y (+a U) (+b V); frag-build VALU hides under MFMA bursts.
// - W1/W2 A-frags in 64KB LDS (ds_read_b128 lane-contiguous, conflict-free);
//   Wl + bl loaded from global in the epilogue.
//
// Layout identity (mfma_f32_16x16x32_bf16, HW-verified m89):
//   D:      ch = 16*mb + 4*(lane>>4) + r,               batch = lane&15
//   B-frag: ch = 32*kb + 16*(j>>2) + 4*(lane>>4)+(j&3),  batch = lane&15
// => frag[e>>3][e&7] = state[e], e = 4*mb + r.  All lane-local.

typedef __attribute__((ext_vector_type(8))) short bf16x8;
typedef __attribute__((ext_vector_type(4))) float f32x4;

constexpr float HS = 0.1f;

__device__ __forceinline__ short bf16s(float f) {
    return (short)__builtin_bit_cast(unsigned short, __float2bfloat16(f));
}
__device__ __forceinline__ float bplo(unsigned u) { return __builtin_bit_cast(float, u << 16); }
__device__ __forceinline__ float bphi(unsigned u) { return __builtin_bit_cast(float, u & 0xffff0000u); }

__device__ __forceinline__ void bias_init(const unsigned (&bp)[16], f32x4 (&acc)[8]) {
    #pragma unroll
    for (int mb = 0; mb < 8; ++mb) {
        acc[mb][0] = bplo(bp[mb * 2 + 0]);
        acc[mb][1] = bphi(bp[mb * 2 + 0]);
        acc[mb][2] = bplo(bp[mb * 2 + 1]);
        acc[mb][3] = bphi(bp[mb * 2 + 1]);
    }
}

// One f-eval with mode-fused arg build and writeback.
template<int M>
__device__ __forceinline__ void feval(const uint4* __restrict__ sw1,
                                      const uint4* __restrict__ sw2, int lane,
                                      const unsigned (&b1p)[16], const unsigned (&b2p)[16],
                                      float (&y)[32], float (&U)[32], float (&V)[32])
{
    // ---- matmul1: acc = W1 @ arg + b1, arg built JIT per kb
    f32x4 acc[8];
    bias_init(b1p, acc);
    #pragma unroll
    for (int kb = 0; kb < 4; ++kb) {
        bf16x8 f;
        #pragma unroll
        for (int j = 0; j < 8; ++j) {
            const int e = kb * 8 + j;
            float a;
            if (M == 1)      a = y[e];
            else if (M == 2) a = fmaf(HS * (1.f / 3.f), U[e], y[e]);
            else if (M == 3) a = fmaf(-HS * (1.f / 3.f), U[e], fmaf(HS, V[e], y[e]));
            else             a = fmaf(HS, V[e], y[e]);
            f[j] = bf16s(a);
        }
        #pragma unroll
        for (int mb = 0; mb < 8; ++mb) {
            bf16x8 w = __builtin_bit_cast(bf16x8, sw1[(mb * 4 + kb) * 64 + lane]);
            acc[mb] = __builtin_amdgcn_mfma_f32_16x16x32_bf16(w, f, acc[mb], 0, 0, 0);
        }
    }
    // ---- relu -> bf16 h frags (frees acc)
    bf16x8 h[4];
    #pragma unroll
    for (int mb = 0; mb < 8; ++mb)
        #pragma unroll
        for (int r = 0; r < 4; ++r)
            h[mb >> 1][(mb & 1) * 4 + r] = bf16s(fmaxf(acc[mb][r], 0.f));
    // ---- matmul2: acc2 = W2 @ h + b2
    f32x4 acc2[8];
    bias_init(b2p, acc2);
    #pragma unroll
    for (int kb = 0; kb < 4; ++kb)
        #pragma unroll
        for (int mb = 0; mb < 8; ++mb) {
            bf16x8 w = __builtin_bit_cast(bf16x8, sw2[(mb * 4 + kb) * 64 + lane]);
            acc2[mb] = __builtin_amdgcn_mfma_f32_16x16x32_bf16(w, h[kb], acc2[mb], 0, 0, 0);
        }
    // ---- mode-fused writeback
    #pragma unroll
    for (int mb = 0; mb < 8; ++mb)
        #pragma unroll
        for (int r = 0; r < 4; ++r) {
            const int e = mb * 4 + r;
            const float k = acc2[mb][r];
            if (M == 1)      U[e] = k;
            else if (M == 2) V[e] = k;
            else if (M == 3) {
                const float u = U[e], v = V[e];
                U[e] = fmaf(3.f, v + k, u);
                V[e] = u - v + k;
            } else {
                y[e] = fmaf(HS * 0.125f, U[e] + k, y[e]);
            }
        }
}

__global__ __launch_bounds__(256) void gnode_kernel(
    const float* __restrict__ x, const uint4* __restrict__ wfr,
    const unsigned* __restrict__ b1pg, const unsigned* __restrict__ b2pg,
    const float* __restrict__ bl, float* __restrict__ out, int n)
{
    __shared__ uint4 s_w[4096];              // 64KB: W1 frags [0..2047], W2 [2048..4095]

    const int tid  = threadIdx.x;
    const int lane = tid & 63;
    const int wid  = tid >> 6;
    const int g    = lane >> 4;
    const int c16  = lane & 15;
    const int row  = blockIdx.x * 64 + wid * 16 + c16;   // this lane's batch row
    const int rowc = row < n ? row : n - 1;

    // ---- stage W1+W2 frags into LDS (one-time, 64KB, L2/L3-hot)
    #pragma unroll
    for (int i = 0; i < 16; ++i) s_w[i * 256 + tid] = wfr[i * 256 + tid];

    unsigned b1p[16], b2p[16];
    #pragma unroll
    for (int p = 0; p < 16; ++p) b1p[p] = b1pg[lane * 16 + p];
    #pragma unroll
    for (int p = 0; p < 16; ++p) b2p[p] = b2pg[lane * 16 + p];

    // Y^T state, fp32 master: elem e=4*mb+r <-> (ch = 16*mb+4*g+r, batch=row)
    float y[32];
    {
        const f32x4* x4 = (const f32x4*)x;
        #pragma unroll
        for (int cb = 0; cb < 8; ++cb) {
            f32x4 v = x4[(size_t)rowc * 32 + cb * 4 + g];
            y[cb * 4 + 0] = v[0]; y[cb * 4 + 1] = v[1];
            y[cb * 4 + 2] = v[2]; y[cb * 4 + 3] = v[3];
        }
    }
    __syncthreads();

    const uint4* sw1 = s_w;
    const uint4* sw2 = s_w + 2048;

    float U[32], V[32];

    for (int st = 0; st < 10; ++st) {
        feval<1>(sw1, sw2, lane, b1p, b2p, y, U, V);   // U <- k1
        feval<2>(sw1, sw2, lane, b1p, b2p, y, U, V);   // V <- k2
        feval<3>(sw1, sw2, lane, b1p, b2p, y, U, V);   // fold k3
        feval<4>(sw1, sw2, lane, b1p, b2p, y, U, V);   // y += h/8 (U + k4)
    }

    // ---- epilogue: out^T = Wl^T y^T + bl  (Wl frags straight from global)
    bf16x8 yf[4];
    #pragma unroll
    for (int e = 0; e < 32; ++e) yf[e >> 3][e & 7] = bf16s(y[e]);
    f32x4 ao[4];
    {
        const f32x4* bl4 = (const f32x4*)bl;
        #pragma unroll
        for (int mb = 0; mb < 4; ++mb) ao[mb] = bl4[mb * 4 + g];   // bl[16mb+4g+r]
    }
    #pragma unroll
    for (int f = 0; f < 16; ++f) {
        bf16x8 w = __builtin_bit_cast(bf16x8, wfr[(64 + f) * 64 + lane]);
        ao[f >> 2] = __builtin_amdgcn_mfma_f32_16x16x32_bf16(w, yf[f & 3], ao[f >> 2], 0, 0, 0);
    }
    if (row < n) {
        f32x4* out4 = (f32x4*)out;
        #pragma unroll
        for (int mb = 0; mb < 4; ++mb)
            out4[(size_t)row * 16 + mb * 4 + g] = ao[mb];          // out[row][16mb+4g+r]
    }
}

// ---- prep: A-frag-linear bf16 weights + packed-bf16 biases into d_ws ----
// A-frag (16x32): lane l, elem j:  row = l&15 (+16*mb),
//                                  k   = 32*kb + 16*(j>>2) + 4*(l>>4) + (j&3)
// wfr[f*64+lane] : f 0..31 = W1 (mb=f>>2,kb=f&3), 32..63 = W2, 64..79 = Wl.
__global__ void prep_kernel(const float* __restrict__ W1, const float* __restrict__ W2,
                            const float* __restrict__ Wl,
                            const float* __restrict__ b1, const float* __restrict__ b2,
                            uint4* __restrict__ wfr, unsigned* __restrict__ b1p,
                            unsigned* __restrict__ b2p)
{
    int t = blockIdx.x * 256 + threadIdx.x;
    if (t < 80 * 64) {
        int f = t >> 6, lane = t & 63;
        int gq = lane >> 4, c = lane & 15;
        const float* W; int mb, kv, cols;
        if (f < 32)      { W = W1; mb = f >> 2;        kv = f & 3;        cols = 128; }
        else if (f < 64) { W = W2; mb = (f - 32) >> 2; kv = (f - 32) & 3; cols = 128; }
        else             { W = Wl; mb = (f - 64) >> 2; kv = (f - 64) & 3; cols = 64;  }
        int col = mb * 16 + c;               // output-channel (A row)
        unsigned short v[8];
        #pragma unroll
        for (int j = 0; j < 8; ++j) {
            int k = kv * 32 + (j >> 2) * 16 + gq * 4 + (j & 3);
            v[j] = __builtin_bit_cast(unsigned short, __float2bfloat16(W[k * cols + col]));
        }
        uint4 o;
        o.x = (unsigned)v[0] | ((unsigned)v[1] << 16);
        o.y = (unsigned)v[2] | ((unsigned)v[3] << 16);
        o.z = (unsigned)v[4] | ((unsigned)v[5] << 16);
        o.w = (unsigned)v[6] | ((unsigned)v[7] << 16);
        wfr[t] = o;
    } else if (t < 80 * 64 + 128) {
        int u = t - 80 * 64;
        const float* b = (u < 64) ? b1 : b2;
        unsigned* dst  = (u < 64) ? b1p : b2p;
        int lane = u & 63, gq = lane >> 4;
        for (int p = 0; p < 16; ++p) {       // pair p covers state elems 2p,2p+1
            int e0 = 2 * p, e1 = 2 * p + 1;
            int ch0 = 16 * (e0 >> 2) + 4 * gq + (e0 & 3);
            int ch1 = 16 * (e1 >> 2) + 4 * gq + (e1 & 3);
            unsigned short v0 = __builtin_bit_cast(unsigned short, __float2bfloat16(b[ch0]));
            unsigned short v1 = __builtin_bit_cast(unsigned short, __float2bfloat16(b[ch1]));
            dst[lane * 16 + p] = (unsigned)v0 | ((unsigned)v1 << 16);
        }
    }
}

extern "C" void kernel_launch(void* const* d_in, const int* in_sizes, int n_in,
                              void* d_out, int out_size, void* d_ws, size_t ws_size,
                              hipStream_t stream)
{
    const float* x  = (const float*)d_in[0];
    const float* W1 = (const float*)d_in[1];
    const float* b1 = (const float*)d_in[2];
    const float* W2 = (const float*)d_in[3];
    const float* b2 = (const float*)d_in[4];
    const float* Wl = (const float*)d_in[5];
    const float* bl = (const float*)d_in[6];

    const int n = in_sizes[0] / 128;

    uint4*    wfr = (uint4*)d_ws;                                  // 80*64*16 = 81920 B
    unsigned* b1p = (unsigned*)((char*)d_ws + 81920);              // 4096 B
    unsigned* b2p = (unsigned*)((char*)d_ws + 86016);              // 4096 B

    prep_kernel<<<21, 256, 0, stream>>>(W1, W2, Wl, b1, b2, wfr, b1p, b2p);

    const int nb = (n + 63) / 64;            // 64 rows per block (4 waves x 16)
    gnode_kernel<<<nb, 256, 0, stream>>>(x, wfr, b1p, b2p, bl, (float*)d_out, n);
}

// Round 6
// 728.176 us; speedup vs baseline: 6.2670x; 1.1651x over previous
//
#include <hip/hip_runtime.h>
#include <hip/hip_bf16.h>

// GNODE fully fused: y' = relu(y@W1+b1)@W2+b2, RK4(3/8) x10 steps (h=0.1),
// out = y@Wl+bl.  N=200000 rows, 128 ch, 64 out ch.
//
// Round 6: stop the scheduler-driven spill seen in r3/r5 (VGPR_Count pinned
// at 256 = arch half of unified 512 file; 1.6GB scratch traffic):
// - biases moved to LDS (p-major, conflict-free)          -> -32 arch VGPRs
// - #pragma unroll 1 on the step loop                     -> no cross-step
//   software pipelining of weight loads
// - sched_barrier(VALU|SALU may cross) after each 8-MFMA kb-group -> at most
//   8 ds_read_b128 weight loads (32 VGPRs) in flight
// Live set: y/U/V 96 + wload 32 + h 16 + frag 4 + temps ~24 = ~172 arch.
//
// State recurrences (template<MODE>):
//   M1: U<-k1   M2: V<-k2   M3: U<-U+3(V+k3), V<-U-V+k3   M4: y+=h/8(U+k4)
// Layout identity (mfma_f32_16x16x32_bf16, HW-verified m89):
//   D:      ch = 16*mb + 4*(lane>>4) + r,               batch = lane&15
//   B-frag: ch = 32*kb + 16*(j>>2) + 4*(lane>>4)+(j&3),  batch = lane&15
// => frag[e>>3][e&7] = state[e], e = 4*mb + r.  All lane-local.

typedef __attribute__((ext_vector_type(8))) short bf16x8;
typedef __attribute__((ext_vector_type(4))) float f32x4;

constexpr float HS = 0.1f;

__device__ __forceinline__ short bf16s(float f) {
    return (short)__builtin_bit_cast(unsigned short, __float2bfloat16(f));
}
__device__ __forceinline__ float bplo(unsigned u) { return __builtin_bit_cast(float, u << 16); }
__device__ __forceinline__ float bphi(unsigned u) { return __builtin_bit_cast(float, u & 0xffff0000u); }

// acc init from LDS biases, p-major: sb[p*64+lane]; pair p -> elems 2p,2p+1.
__device__ __forceinline__ void bias_init_lds(const unsigned* __restrict__ sb,
                                              int lane, f32x4 (&acc)[8]) {
    #pragma unroll
    for (int p = 0; p < 16; ++p) {
        unsigned u = sb[p * 64 + lane];
        acc[p >> 1][(p & 1) * 2 + 0] = bplo(u);
        acc[p >> 1][(p & 1) * 2 + 1] = bphi(u);
    }
}

// One f-eval with mode-fused arg build and writeback.
template<int M>
__device__ __forceinline__ void feval(const uint4* __restrict__ sw1,
                                      const uint4* __restrict__ sw2,
                                      const unsigned* __restrict__ sb1,
                                      const unsigned* __restrict__ sb2, int lane,
                                      float (&y)[32], float (&U)[32], float (&V)[32])
{
    // ---- matmul1: acc = W1 @ arg + b1, arg built JIT per kb
    f32x4 acc[8];
    bias_init_lds(sb1, lane, acc);
    #pragma unroll
    for (int kb = 0; kb < 4; ++kb) {
        bf16x8 f;
        #pragma unroll
        for (int j = 0; j < 8; ++j) {
            const int e = kb * 8 + j;
            float a;
            if (M == 1)      a = y[e];
            else if (M == 2) a = fmaf(HS * (1.f / 3.f), U[e], y[e]);
            else if (M == 3) a = fmaf(-HS * (1.f / 3.f), U[e], fmaf(HS, V[e], y[e]));
            else             a = fmaf(HS, V[e], y[e]);
            f[j] = bf16s(a);
        }
        #pragma unroll
        for (int mb = 0; mb < 8; ++mb) {
            bf16x8 w = __builtin_bit_cast(bf16x8, sw1[(mb * 4 + kb) * 64 + lane]);
            acc[mb] = __builtin_amdgcn_mfma_f32_16x16x32_bf16(w, f, acc[mb], 0, 0, 0);
        }
        __builtin_amdgcn_sched_barrier(0x6);   // only VALU/SALU may cross
    }
    // ---- relu -> bf16 h frags (frees acc)
    bf16x8 h[4];
    #pragma unroll
    for (int mb = 0; mb < 8; ++mb)
        #pragma unroll
        for (int r = 0; r < 4; ++r)
            h[mb >> 1][(mb & 1) * 4 + r] = bf16s(fmaxf(acc[mb][r], 0.f));
    __builtin_amdgcn_sched_barrier(0x6);
    // ---- matmul2: acc2 = W2 @ h + b2
    f32x4 acc2[8];
    bias_init_lds(sb2, lane, acc2);
    #pragma unroll
    for (int kb = 0; kb < 4; ++kb) {
        #pragma unroll
        for (int mb = 0; mb < 8; ++mb) {
            bf16x8 w = __builtin_bit_cast(bf16x8, sw2[(mb * 4 + kb) * 64 + lane]);
            acc2[mb] = __builtin_amdgcn_mfma_f32_16x16x32_bf16(w, h[kb], acc2[mb], 0, 0, 0);
        }
        __builtin_amdgcn_sched_barrier(0x6);
    }
    // ---- mode-fused writeback
    #pragma unroll
    for (int mb = 0; mb < 8; ++mb)
        #pragma unroll
        for (int r = 0; r < 4; ++r) {
            const int e = mb * 4 + r;
            const float k = acc2[mb][r];
            if (M == 1)      U[e] = k;
            else if (M == 2) V[e] = k;
            else if (M == 3) {
                const float u = U[e], v = V[e];
                U[e] = fmaf(3.f, v + k, u);
                V[e] = u - v + k;
            } else {
                y[e] = fmaf(HS * 0.125f, U[e] + k, y[e]);
            }
        }
    __builtin_amdgcn_sched_barrier(0x6);
}

__global__ __launch_bounds__(256) void gnode_kernel(
    const float* __restrict__ x, const uint4* __restrict__ wfr,
    const unsigned* __restrict__ b1pg, const unsigned* __restrict__ b2pg,
    const float* __restrict__ bl, float* __restrict__ out, int n)
{
    __shared__ uint4 s_w[4096];      // 64KB: W1 frags [0..2047], W2 [2048..4095]
    __shared__ unsigned s_b[2048];   // 8KB: b1 packed [0..1023], b2 [1024..2047]

    const int tid  = threadIdx.x;
    const int lane = tid & 63;
    const int wid  = tid >> 6;
    const int g    = lane >> 4;
    const int c16  = lane & 15;
    const int row  = blockIdx.x * 64 + wid * 16 + c16;   // this lane's batch row
    const int rowc = row < n ? row : n - 1;

    // ---- stage weights + biases into LDS (one-time, L2/L3-hot)
    #pragma unroll
    for (int i = 0; i < 16; ++i) s_w[i * 256 + tid] = wfr[i * 256 + tid];
    #pragma unroll
    for (int i = 0; i < 4; ++i) s_b[i * 256 + tid] = b1pg[i * 256 + tid];
    #pragma unroll
    for (int i = 0; i < 4; ++i) s_b[1024 + i * 256 + tid] = b2pg[i * 256 + tid];

    // Y^T state, fp32 master: elem e=4*mb+r <-> (ch = 16*mb+4*g+r, batch=row)
    float y[32];
    {
        const f32x4* x4 = (const f32x4*)x;
        #pragma unroll
        for (int cb = 0; cb < 8; ++cb) {
            f32x4 v = x4[(size_t)rowc * 32 + cb * 4 + g];
            y[cb * 4 + 0] = v[0]; y[cb * 4 + 1] = v[1];
            y[cb * 4 + 2] = v[2]; y[cb * 4 + 3] = v[3];
        }
    }
    __syncthreads();

    const uint4*    sw1 = s_w;
    const uint4*    sw2 = s_w + 2048;
    const unsigned* sb1 = s_b;
    const unsigned* sb2 = s_b + 1024;

    float U[32], V[32];

    #pragma unroll 1
    for (int st = 0; st < 10; ++st) {
        feval<1>(sw1, sw2, sb1, sb2, lane, y, U, V);   // U <- k1
        feval<2>(sw1, sw2, sb1, sb2, lane, y, U, V);   // V <- k2
        feval<3>(sw1, sw2, sb1, sb2, lane, y, U, V);   // fold k3
        feval<4>(sw1, sw2, sb1, sb2, lane, y, U, V);   // y += h/8 (U + k4)
    }

    // ---- epilogue: out^T = Wl^T y^T + bl  (Wl frags straight from global)
    bf16x8 yf[4];
    #pragma unroll
    for (int e = 0; e < 32; ++e) yf[e >> 3][e & 7] = bf16s(y[e]);
    f32x4 ao[4];
    {
        const f32x4* bl4 = (const f32x4*)bl;
        #pragma unroll
        for (int mb = 0; mb < 4; ++mb) ao[mb] = bl4[mb * 4 + g];   // bl[16mb+4g+r]
    }
    #pragma unroll
    for (int f = 0; f < 16; ++f) {
        bf16x8 w = __builtin_bit_cast(bf16x8, wfr[(64 + f) * 64 + lane]);
        ao[f >> 2] = __builtin_amdgcn_mfma_f32_16x16x32_bf16(w, yf[f & 3], ao[f >> 2], 0, 0, 0);
    }
    if (row < n) {
        f32x4* out4 = (f32x4*)out;
        #pragma unroll
        for (int mb = 0; mb < 4; ++mb)
            out4[(size_t)row * 16 + mb * 4 + g] = ao[mb];          // out[row][16mb+4g+r]
    }
}

// ---- prep: A-frag-linear bf16 weights + packed-bf16 biases into d_ws ----
// A-frag (16x32): lane l, elem j:  row = l&15 (+16*mb),
//                                  k   = 32*kb + 16*(j>>2) + 4*(l>>4) + (j&3)
// wfr[f*64+lane] : f 0..31 = W1 (mb=f>>2,kb=f&3), 32..63 = W2, 64..79 = Wl.
// biases: p-major pairs, dst[p*64+lane] covers state elems 2p,2p+1.
__global__ void prep_kernel(const float* __restrict__ W1, const float* __restrict__ W2,
                            const float* __restrict__ Wl,
                            const float* __restrict__ b1, const float* __restrict__ b2,
                            uint4* __restrict__ wfr, unsigned* __restrict__ b1p,
                            unsigned* __restrict__ b2p)
{
    int t = blockIdx.x * 256 + threadIdx.x;
    if (t < 80 * 64) {
        int f = t >> 6, lane = t & 63;
        int gq = lane >> 4, c = lane & 15;
        const float* W; int mb, kv, cols;
        if (f < 32)      { W = W1; mb = f >> 2;        kv = f & 3;        cols = 128; }
        else if (f < 64) { W = W2; mb = (f - 32) >> 2; kv = (f - 32) & 3; cols = 128; }
        else             { W = Wl; mb = (f - 64) >> 2; kv = (f - 64) & 3; cols = 64;  }
        int col = mb * 16 + c;               // output-channel (A row)
        unsigned short v[8];
        #pragma unroll
        for (int j = 0; j < 8; ++j) {
            int k = kv * 32 + (j >> 2) * 16 + gq * 4 + (j & 3);
            v[j] = __builtin_bit_cast(unsigned short, __float2bfloat16(W[k * cols + col]));
        }
        uint4 o;
        o.x = (unsigned)v[0] | ((unsigned)v[1] << 16);
        o.y = (unsigned)v[2] | ((unsigned)v[3] << 16);
        o.z = (unsigned)v[4] | ((unsigned)v[5] << 16);
        o.w = (unsigned)v[6] | ((unsigned)v[7] << 16);
        wfr[t] = o;
    } else if (t < 80 * 64 + 128) {
        int u = t - 80 * 64;
        const float* b = (u < 64) ? b1 : b2;
        unsigned* dst  = (u < 64) ? b1p : b2p;
        int lane = u & 63, gq = lane >> 4;
        for (int p = 0; p < 16; ++p) {       // pair p covers state elems 2p,2p+1
            int e0 = 2 * p, e1 = 2 * p + 1;
            int ch0 = 16 * (e0 >> 2) + 4 * gq + (e0 & 3);
            int ch1 = 16 * (e1 >> 2) + 4 * gq + (e1 & 3);
            unsigned short v0 = __builtin_bit_cast(unsigned short, __float2bfloat16(b[ch0]));
            unsigned short v1 = __builtin_bit_cast(unsigned short, __float2bfloat16(b[ch1]));
            dst[p * 64 + lane] = (unsigned)v0 | ((unsigned)v1 << 16);
        }
    }
}

extern "C" void kernel_launch(void* const* d_in, const int* in_sizes, int n_in,
                              void* d_out, int out_size, void* d_ws, size_t ws_size,
                              hipStream_t stream)
{
    const float* x  = (const float*)d_in[0];
    const float* W1 = (const float*)d_in[1];
    const float* b1 = (const float*)d_in[2];
    const float* W2 = (const float*)d_in[3];
    const float* b2 = (const float*)d_in[4];
    const float* Wl = (const float*)d_in[5];
    const float* bl = (const float*)d_in[6];

    const int n = in_sizes[0] / 128;

    uint4*    wfr = (uint4*)d_ws;                                  // 80*64*16 = 81920 B
    unsigned* b1p = (unsigned*)((char*)d_ws + 81920);              // 4096 B
    unsigned* b2p = (unsigned*)((char*)d_ws + 86016);              // 4096 B

    prep_kernel<<<21, 256, 0, stream>>>(W1, W2, Wl, b1, b2, wfr, b1p, b2p);

    const int nb = (n + 63) / 64;            // 64 rows per block (4 waves x 16)
    gnode_kernel<<<nb, 256, 0, stream>>>(x, wfr, b1p, b2p, bl, (float*)d_out, n);
}

// Round 7
// 578.390 us; speedup vs baseline: 7.8899x; 1.2590x over previous
//
#include <hip/hip_runtime.h>
#include <hip/hip_bf16.h>

// GNODE fully fused: y' = relu(y@W1+b1)@W2+b2, RK4(3/8) x10 steps (h=0.1),
// out = y@Wl+bl.  N=200000 rows, 128 ch, 64 out ch.
//
// Round 7: r6 killed the spill (FETCH+WRITE = exactly in+out) but serialized
// ds_read -> MFMA (sched_barrier blocked all weight prefetch): MfmaUtil 26%.
// Changes:
// - explicit 1-group-deep weight prefetch: two named buffers wA/wB (32+32
//   regs, static indexing only); group g+1's 8 ds_read_b128 issue in the
//   same sched region as group g's 8 MFMAs -> loads hide under MFMA burst.
// - biases staged as raw f32 in LDS (natural order): acc init = 8 broadcast
//   ds_read_b128, zero unpack VALU (was 16 reads + 32 unpacks).
// - no trailing sched_barrier after writeback: next feval's group-0 loads
//   hoist into writeback VALU.
// - sched_barrier(0x6) (VALU|SALU may cross) still fences each MFMA group:
//   bounds scheduler hoisting -> no r5-style register blowup.
//
// State recurrences (template<MODE>):
//   M1: U<-k1   M2: V<-k2   M3: U<-U+3(V+k3), V<-U-V+k3   M4: y+=h/8(U+k4)
// Layout identity (mfma_f32_16x16x32_bf16, HW-verified m89):
//   D:      ch = 16*mb + 4*(lane>>4) + r,               batch = lane&15
//   B-frag: ch = 32*kb + 16*(j>>2) + 4*(lane>>4)+(j&3),  batch = lane&15
// => frag[e>>3][e&7] = state[e], e = 4*mb + r.  All lane-local.

typedef __attribute__((ext_vector_type(8))) short bf16x8;
typedef __attribute__((ext_vector_type(4))) float f32x4;

constexpr float HS = 0.1f;

__device__ __forceinline__ short bf16s(float f) {
    return (short)__builtin_bit_cast(unsigned short, __float2bfloat16(f));
}

#define MFMA_BF16 __builtin_amdgcn_mfma_f32_16x16x32_bf16
#define SBAR() __builtin_amdgcn_sched_barrier(0x6)

template<int M>
__device__ __forceinline__ bf16x8 build_frag(const float (&y)[32], const float (&U)[32],
                                             const float (&V)[32], int kb) {
    bf16x8 f;
    #pragma unroll
    for (int j = 0; j < 8; ++j) {
        const int e = kb * 8 + j;
        float a;
        if (M == 1)      a = y[e];
        else if (M == 2) a = fmaf(HS * (1.f / 3.f), U[e], y[e]);
        else if (M == 3) a = fmaf(-HS * (1.f / 3.f), U[e], fmaf(HS, V[e], y[e]));
        else             a = fmaf(HS, V[e], y[e]);
        f[j] = bf16s(a);
    }
    return f;
}

// One f-eval, 8 MFMA groups, 1-group-deep weight prefetch (wA/wB ping-pong).
template<int M>
__device__ __forceinline__ void feval(const uint4* __restrict__ sw1,
                                      const uint4* __restrict__ sw2,
                                      const float* __restrict__ sbf, int lane, int g,
                                      float (&y)[32], float (&U)[32], float (&V)[32])
{
    uint4 wA[8], wB[8];

    // acc = b1 (broadcast f32x4 reads, no VALU)
    f32x4 acc[8];
    #pragma unroll
    for (int mb = 0; mb < 8; ++mb)
        acc[mb] = *(const f32x4*)&sbf[mb * 16 + g * 4];
    // prefetch W1 group 0
    #pragma unroll
    for (int mb = 0; mb < 8; ++mb) wA[mb] = sw1[(mb * 4 + 0) * 64 + lane];

    // ---- matmul1 groups 0..3 ----
    bf16x8 f0 = build_frag<M>(y, U, V, 0);
    #pragma unroll
    for (int mb = 0; mb < 8; ++mb) wB[mb] = sw1[(mb * 4 + 1) * 64 + lane];
    #pragma unroll
    for (int mb = 0; mb < 8; ++mb)
        acc[mb] = MFMA_BF16(__builtin_bit_cast(bf16x8, wA[mb]), f0, acc[mb], 0, 0, 0);
    SBAR();

    bf16x8 f1 = build_frag<M>(y, U, V, 1);
    #pragma unroll
    for (int mb = 0; mb < 8; ++mb) wA[mb] = sw1[(mb * 4 + 2) * 64 + lane];
    #pragma unroll
    for (int mb = 0; mb < 8; ++mb)
        acc[mb] = MFMA_BF16(__builtin_bit_cast(bf16x8, wB[mb]), f1, acc[mb], 0, 0, 0);
    SBAR();

    bf16x8 f2 = build_frag<M>(y, U, V, 2);
    #pragma unroll
    for (int mb = 0; mb < 8; ++mb) wB[mb] = sw1[(mb * 4 + 3) * 64 + lane];
    #pragma unroll
    for (int mb = 0; mb < 8; ++mb)
        acc[mb] = MFMA_BF16(__builtin_bit_cast(bf16x8, wA[mb]), f2, acc[mb], 0, 0, 0);
    SBAR();

    bf16x8 f3 = build_frag<M>(y, U, V, 3);
    #pragma unroll
    for (int mb = 0; mb < 8; ++mb) wA[mb] = sw2[(mb * 4 + 0) * 64 + lane];   // W2 grp0
    #pragma unroll
    for (int mb = 0; mb < 8; ++mb)
        acc[mb] = MFMA_BF16(__builtin_bit_cast(bf16x8, wB[mb]), f3, acc[mb], 0, 0, 0);
    SBAR();

    // ---- relu -> h frags; acc2 = b2 ----
    bf16x8 h[4];
    #pragma unroll
    for (int mb = 0; mb < 8; ++mb)
        #pragma unroll
        for (int r = 0; r < 4; ++r)
            h[mb >> 1][(mb & 1) * 4 + r] = bf16s(fmaxf(acc[mb][r], 0.f));
    f32x4 acc2[8];
    #pragma unroll
    for (int mb = 0; mb < 8; ++mb)
        acc2[mb] = *(const f32x4*)&sbf[128 + mb * 16 + g * 4];

    // ---- matmul2 groups 4..7 ----
    #pragma unroll
    for (int mb = 0; mb < 8; ++mb) wB[mb] = sw2[(mb * 4 + 1) * 64 + lane];
    #pragma unroll
    for (int mb = 0; mb < 8; ++mb)
        acc2[mb] = MFMA_BF16(__builtin_bit_cast(bf16x8, wA[mb]), h[0], acc2[mb], 0, 0, 0);
    SBAR();

    #pragma unroll
    for (int mb = 0; mb < 8; ++mb) wA[mb] = sw2[(mb * 4 + 2) * 64 + lane];
    #pragma unroll
    for (int mb = 0; mb < 8; ++mb)
        acc2[mb] = MFMA_BF16(__builtin_bit_cast(bf16x8, wB[mb]), h[1], acc2[mb], 0, 0, 0);
    SBAR();

    #pragma unroll
    for (int mb = 0; mb < 8; ++mb) wB[mb] = sw2[(mb * 4 + 3) * 64 + lane];
    #pragma unroll
    for (int mb = 0; mb < 8; ++mb)
        acc2[mb] = MFMA_BF16(__builtin_bit_cast(bf16x8, wA[mb]), h[2], acc2[mb], 0, 0, 0);
    SBAR();

    #pragma unroll
    for (int mb = 0; mb < 8; ++mb)
        acc2[mb] = MFMA_BF16(__builtin_bit_cast(bf16x8, wB[mb]), h[3], acc2[mb], 0, 0, 0);
    SBAR();

    // ---- mode-fused writeback (no trailing fence: next feval's loads may hoist)
    #pragma unroll
    for (int mb = 0; mb < 8; ++mb)
        #pragma unroll
        for (int r = 0; r < 4; ++r) {
            const int e = mb * 4 + r;
            const float k = acc2[mb][r];
            if (M == 1)      U[e] = k;
            else if (M == 2) V[e] = k;
            else if (M == 3) {
                const float u = U[e], v = V[e];
                U[e] = fmaf(3.f, v + k, u);
                V[e] = u - v + k;
            } else {
                y[e] = fmaf(HS * 0.125f, U[e] + k, y[e]);
            }
        }
}

__global__ __launch_bounds__(256) void gnode_kernel(
    const float* __restrict__ x, const uint4* __restrict__ wfr,
    const float* __restrict__ b1, const float* __restrict__ b2,
    const float* __restrict__ bl, float* __restrict__ out, int n)
{
    __shared__ uint4 s_w[4096];      // 64KB: W1 frags [0..2047], W2 [2048..4095]
    __shared__ float s_bf[256];      // 1KB: b1 [0..127], b2 [128..255]

    const int tid  = threadIdx.x;
    const int lane = tid & 63;
    const int wid  = tid >> 6;
    const int g    = lane >> 4;
    const int c16  = lane & 15;
    const int row  = blockIdx.x * 64 + wid * 16 + c16;   // this lane's batch row
    const int rowc = row < n ? row : n - 1;

    // ---- stage weights + biases into LDS (one-time, L2/L3-hot)
    #pragma unroll
    for (int i = 0; i < 16; ++i) s_w[i * 256 + tid] = wfr[i * 256 + tid];
    s_bf[tid] = (tid < 128) ? b1[tid] : b2[tid - 128];

    // Y^T state, fp32 master: elem e=4*mb+r <-> (ch = 16*mb+4*g+r, batch=row)
    float y[32];
    {
        const f32x4* x4 = (const f32x4*)x;
        #pragma unroll
        for (int cb = 0; cb < 8; ++cb) {
            f32x4 v = x4[(size_t)rowc * 32 + cb * 4 + g];
            y[cb * 4 + 0] = v[0]; y[cb * 4 + 1] = v[1];
            y[cb * 4 + 2] = v[2]; y[cb * 4 + 3] = v[3];
        }
    }
    __syncthreads();

    const uint4* sw1 = s_w;
    const uint4* sw2 = s_w + 2048;

    float U[32], V[32];

    #pragma unroll 1
    for (int st = 0; st < 10; ++st) {
        feval<1>(sw1, sw2, s_bf, lane, g, y, U, V);   // U <- k1
        feval<2>(sw1, sw2, s_bf, lane, g, y, U, V);   // V <- k2
        feval<3>(sw1, sw2, s_bf, lane, g, y, U, V);   // fold k3
        feval<4>(sw1, sw2, s_bf, lane, g, y, U, V);   // y += h/8 (U + k4)
    }

    // ---- epilogue: out^T = Wl^T y^T + bl  (Wl frags straight from global)
    bf16x8 yf[4];
    #pragma unroll
    for (int e = 0; e < 32; ++e) yf[e >> 3][e & 7] = bf16s(y[e]);
    f32x4 ao[4];
    {
        const f32x4* bl4 = (const f32x4*)bl;
        #pragma unroll
        for (int mb = 0; mb < 4; ++mb) ao[mb] = bl4[mb * 4 + g];   // bl[16mb+4g+r]
    }
    #pragma unroll
    for (int f = 0; f < 16; ++f) {
        bf16x8 w = __builtin_bit_cast(bf16x8, wfr[(64 + f) * 64 + lane]);
        ao[f >> 2] = MFMA_BF16(w, yf[f & 3], ao[f >> 2], 0, 0, 0);
    }
    if (row < n) {
        f32x4* out4 = (f32x4*)out;
        #pragma unroll
        for (int mb = 0; mb < 4; ++mb)
            out4[(size_t)row * 16 + mb * 4 + g] = ao[mb];          // out[row][16mb+4g+r]
    }
}

// ---- prep: A-frag-linear bf16 weights into d_ws ----
// A-frag (16x32): lane l, elem j:  row = l&15 (+16*mb),
//                                  k   = 32*kb + 16*(j>>2) + 4*(l>>4) + (j&3)
// wfr[f*64+lane] : f 0..31 = W1 (mb=f>>2,kb=f&3), 32..63 = W2, 64..79 = Wl.
__global__ void prep_kernel(const float* __restrict__ W1, const float* __restrict__ W2,
                            const float* __restrict__ Wl, uint4* __restrict__ wfr)
{
    int t = blockIdx.x * 256 + threadIdx.x;
    if (t >= 80 * 64) return;
    int f = t >> 6, lane = t & 63;
    int gq = lane >> 4, c = lane & 15;
    const float* W; int mb, kv, cols;
    if (f < 32)      { W = W1; mb = f >> 2;        kv = f & 3;        cols = 128; }
    else if (f < 64) { W = W2; mb = (f - 32) >> 2; kv = (f - 32) & 3; cols = 128; }
    else             { W = Wl; mb = (f - 64) >> 2; kv = (f - 64) & 3; cols = 64;  }
    int col = mb * 16 + c;               // output-channel (A row)
    unsigned short v[8];
    #pragma unroll
    for (int j = 0; j < 8; ++j) {
        int k = kv * 32 + (j >> 2) * 16 + gq * 4 + (j & 3);
        v[j] = __builtin_bit_cast(unsigned short, __float2bfloat16(W[k * cols + col]));
    }
    uint4 o;
    o.x = (unsigned)v[0] | ((unsigned)v[1] << 16);
    o.y = (unsigned)v[2] | ((unsigned)v[3] << 16);
    o.z = (unsigned)v[4] | ((unsigned)v[5] << 16);
    o.w = (unsigned)v[6] | ((unsigned)v[7] << 16);
    wfr[t] = o;
}

extern "C" void kernel_launch(void* const* d_in, const int* in_sizes, int n_in,
                              void* d_out, int out_size, void* d_ws, size_t ws_size,
                              hipStream_t stream)
{
    const float* x  = (const float*)d_in[0];
    const float* W1 = (const float*)d_in[1];
    const float* b1 = (const float*)d_in[2];
    const float* W2 = (const float*)d_in[3];
    const float* b2 = (const float*)d_in[4];
    const float* Wl = (const float*)d_in[5];
    const float* bl = (const float*)d_in[6];

    const int n = in_sizes[0] / 128;

    uint4* wfr = (uint4*)d_ws;                       // 80*64*16 = 81920 B

    prep_kernel<<<20, 256, 0, stream>>>(W1, W2, Wl, wfr);

    const int nb = (n + 63) / 64;            // 64 rows per block (4 waves x 16)
    gnode_kernel<<<nb, 256, 0, stream>>>(x, wfr, b1, b2, bl, (float*)d_out, n);
}